// Round 8
// baseline (88.713 us; speedup 1.0000x reference)
//
#include <hip/hip_runtime.h>
#include <math.h>

#define VOCABN 6
#define DIM 32
#define PADI 5
#define BATCH 256
#define SEQ 4096
#define KSEL 614   // int(4096 * 0.15)

// bits of 64-bit mask set at lanes strictly below mine (v_mbcnt_lo + v_mbcnt_hi)
__device__ __forceinline__ int mbcnt64(unsigned long long m) {
    return __builtin_amdgcn_mbcnt_hi((unsigned)(m >> 32),
           __builtin_amdgcn_mbcnt_lo((unsigned)m, 0u));
}

// 6-way register LUT (compile-time indices -> cndmask chain, no LDS)
__device__ __forceinline__ float lut6(float s0, float s1, float s2, float s3,
                                      float s4, float s5, int tk) {
    float r = s0;
    r = (tk == 1) ? s1 : r;
    r = (tk == 2) ? s2 : r;
    r = (tk == 3) ? s3 : r;
    r = (tk == 4) ? s4 : r;
    r = (tk == 5) ? s5 : r;
    return r;
}

// One block per batch row, 1024 threads (16 waves), two barriers.
// R7: selector MLP moved PRE-B0 into wave 0 reading GLOBAL weights (one wave
// gathering is cheap; R3's regression was all 16 doing it). s_score is ready
// at B0, so the 4 MB scores store issues right after B0; B1 only gates the
// 0.6 MB scatter + pred tail. Selector weights no longer staged (-544 loads).
__global__ __launch_bounds__(1024) void fused_row_kernel(
    const int* __restrict__ x,
    const float* __restrict__ emb,
    const float* __restrict__ sel_w1, const float* __restrict__ sel_b1,
    const float* __restrict__ sel_w2, const float* __restrict__ sel_b2,
    const float* __restrict__ app_w1, const float* __restrict__ app_b1,
    const float* __restrict__ app_w2, const float* __restrict__ app_b2,
    const float* __restrict__ cls_w1, const float* __restrict__ cls_b1,
    const float* __restrict__ cls_w2, const float* __restrict__ cls_b2,
    float* __restrict__ out_pred,
    float* __restrict__ out_topidx,
    float* __restrict__ out_scores) {
    const int b = blockIdx.x;
    const int t = threadIdx.x;
    const int lane = t & 63;
    const int w = t >> 6;          // 16 waves

    __shared__ float s_emb[VOCABN * DIM];        // 192 (row PADI zeroed)
    __shared__ float s_appw1[DIM * DIM];         // 1024
    __shared__ float s_appw2[DIM * DIM];         // 1024
    __shared__ float s_appb1[DIM], s_appb2[DIM];
    __shared__ float s_clsw1[DIM * (DIM / 2)];   // 512
    __shared__ float s_clsb1[DIM / 2], s_clsw2[DIM / 2];
    __shared__ float s_clsb2v;
    __shared__ float s_ah[VOCABN * DIM];         // 192 app hidden
    __shared__ __align__(16) float s_score[8];
    __shared__ __align__(16) int s_wtot[16][8];  // per-wave totals (padded row)
    __shared__ __align__(16) int s_wpre[16][8];  // cross-wave exclusive prefix
    __shared__ __align__(16) int s_selbase[8];   // take | (base<<16)

    // --- issue token load first (latency overlaps everything below) ---
    const int4 tw = *(const int4*)(x + (size_t)b * SEQ + t * 4);

    // --- cooperative staging of app/cls weights (selector NOT staged) ---
    s_appw1[t] = app_w1[t];
    s_appw2[t] = app_w2[t];
    if (t >= 512 && t < 1024) s_clsw1[t - 512] = cls_w1[t - 512];
    if (t >= 192 && t < 384) { int i = t - 192; s_emb[i] = (i >= PADI * DIM) ? 0.f : emb[i]; }
    else if (t < 416 && t >= 384) { int i = t - 384; s_appb1[i] = app_b1[i]; }
    else if (t < 448 && t >= 416) { int i = t - 416; s_appb2[i] = app_b2[i]; }
    else if (t < 464 && t >= 448) { int i = t - 448; s_clsb1[i] = cls_b1[i]; }
    else if (t < 480 && t >= 464) { int i = t - 464; s_clsw2[i] = cls_w2[i]; }
    else if (t == 480) s_clsb2v = cls_b2[0];

    int tok[4];
    tok[0] = tw.x; tok[1] = tw.y; tok[2] = tw.z; tok[3] = tw.w;

    // --- wave 0: selector MLP from GLOBAL weights (overlaps staging) ---
    float scv[VOCABN];
    if (w == 0) {
        int sv = lane >> 3; if (sv >= VOCABN) sv -= VOCABN;   // lanes 48-63 redundant
        const int j0 = (lane & 7) * 2;
        const float2 bj = *(const float2*)(sel_b1 + j0);
        const float2 wj = *(const float2*)(sel_w2 + j0);
        float h0 = bj.x, h1 = bj.y;
        if (sv != PADI) {
            const float4* e4 = (const float4*)(emb + sv * DIM);
            #pragma unroll
            for (int q = 0; q < 8; ++q) {
                const float4 e = e4[q];
                const float2 wa = *(const float2*)(sel_w1 + (q * 4 + 0) * (DIM / 2) + j0);
                const float2 wb = *(const float2*)(sel_w1 + (q * 4 + 1) * (DIM / 2) + j0);
                const float2 wc = *(const float2*)(sel_w1 + (q * 4 + 2) * (DIM / 2) + j0);
                const float2 wd = *(const float2*)(sel_w1 + (q * 4 + 3) * (DIM / 2) + j0);
                h0 += e.x * wa.x + e.y * wb.x + e.z * wc.x + e.w * wd.x;
                h1 += e.x * wa.y + e.y * wb.y + e.z * wc.y + e.w * wd.y;
            }
        }
        float part = fmaxf(h0, 0.f) * wj.x + fmaxf(h1, 0.f) * wj.y;
        part += __shfl_xor(part, 1, 64);
        part += __shfl_xor(part, 2, 64);
        part += __shfl_xor(part, 4, 64);
        const float sig = 1.f / (1.f + expf(-(part + sel_b2[0])));
        #pragma unroll
        for (int v = 0; v < VOCABN; ++v) scv[v] = __shfl(sig, v * 8, 64);
        if (lane < VOCABN) s_score[lane] = scv[lane];
    }

    // --- histogram via ballot (VALU/SALU only; no LDS pipe) ---
    unsigned long long msk[VOCABN][4];
    #pragma unroll
    for (int v = 0; v < VOCABN; ++v) {
        #pragma unroll
        for (int i = 0; i < 4; ++i) msk[v][i] = __ballot(tok[i] == v);
    }
    if (lane == 0) {
        int c[VOCABN];
        #pragma unroll
        for (int v = 0; v < VOCABN; ++v)
            c[v] = __popcll(msk[v][0]) + __popcll(msk[v][1]) +
                   __popcll(msk[v][2]) + __popcll(msk[v][3]);
        *(int4*)&s_wtot[w][0] = make_int4(c[0], c[1], c[2], c[3]);
        *(int2*)&s_wtot[w][4] = make_int2(c[4], c[5]);
    }

    __syncthreads();   // B0: staging + wtot + s_score visible

    // --- bulk 4 MB scores store: issues immediately after B0 ---
    {
        const float4 s03 = *(const float4*)&s_score[0];
        const float2 s45 = *(const float2*)&s_score[4];
        float4 f;
        f.x = lut6(s03.x, s03.y, s03.z, s03.w, s45.x, s45.y, tok[0]);
        f.y = lut6(s03.x, s03.y, s03.z, s03.w, s45.x, s45.y, tok[1]);
        f.z = lut6(s03.x, s03.y, s03.z, s03.w, s45.x, s45.y, tok[2]);
        f.w = lut6(s03.x, s03.y, s03.z, s03.w, s45.x, s45.y, tok[3]);
        *(float4*)(out_scores + (size_t)b * SEQ + t * 4) = f;
    }

    if (w == 0) {
        // rank/take: totals via row-read + xor-reduce, scores already in regs
        int tv[VOCABN];
        #pragma unroll
        for (int v = 0; v < VOCABN; ++v) tv[v] = s_wtot[lane & 15][v];
        #pragma unroll
        for (int m = 1; m <= 8; m <<= 1) {
            #pragma unroll
            for (int v = 0; v < VOCABN; ++v) tv[v] += __shfl_xor(tv[v], m, 64);
        }
        int rk[VOCABN];
        #pragma unroll
        for (int v = 0; v < VOCABN; ++v) {
            int r = 0;
            #pragma unroll
            for (int u = 0; u < VOCABN; ++u) {
                if (scv[u] > scv[v]) ++r;
                else if (scv[u] == scv[v] && u < v) ++r;
            }
            rk[v] = r;
        }
        if (lane < VOCABN) {
            const int v = lane;
            int before = 0;
            #pragma unroll
            for (int u = 0; u < VOCABN; ++u) before += (rk[u] < rk[v]) ? tv[u] : 0;
            const int base = before < KSEL ? before : KSEL;
            int take = KSEL - base;
            take = tv[v] < take ? tv[v] : take;
            take = take > 0 ? take : 0;
            s_selbase[v] = take | (base << 16);
        }
    } else if (w == 1) {
        // cross-wave exclusive prefix of wtot -> s_wpre
        int tv[VOCABN], inc[VOCABN];
        #pragma unroll
        for (int v = 0; v < VOCABN; ++v) { tv[v] = s_wtot[lane & 15][v]; inc[v] = tv[v]; }
        #pragma unroll
        for (int off = 1; off <= 8; off <<= 1) {
            #pragma unroll
            for (int v = 0; v < VOCABN; ++v) {
                int up = __shfl_up(inc[v], off, 64);
                if ((lane & 15) >= off) inc[v] += up;
            }
        }
        if (lane < 16) {
            *(int4*)&s_wpre[lane][0] = make_int4(inc[0] - tv[0], inc[1] - tv[1],
                                                 inc[2] - tv[2], inc[3] - tv[3]);
            *(int2*)&s_wpre[lane][4] = make_int2(inc[4] - tv[4], inc[5] - tv[5]);
        }
    } else if (w >= 2 && w < 5) {
        // approximator hidden layer: 192 threads
        const int i = t - 128, v = i >> 5, j = i & 31;
        float acc = s_appb1[j];
        #pragma unroll
        for (int d = 0; d < DIM; ++d) acc += s_emb[v * DIM + d] * s_appw1[d * DIM + j];
        s_ah[i] = fmaxf(acc, 0.f);
    }

    __syncthreads();   // B1: selbase, wpre, ah visible

    // --- scatter top_idx: wave-uniform metadata via 4 vector LDS reads ---
    {
        const int4 wp03 = *(const int4*)&s_wpre[w][0];
        const int2 wp45 = *(const int2*)&s_wpre[w][4];
        const int4 sb03 = *(const int4*)&s_selbase[0];
        const int2 sb45 = *(const int2*)&s_selbase[4];
        const int wp[VOCABN] = {wp03.x, wp03.y, wp03.z, wp03.w, wp45.x, wp45.y};
        const int sb[VOCABN] = {sb03.x, sb03.y, sb03.z, sb03.w, sb45.x, sb45.y};
        #pragma unroll
        for (int v = 0; v < VOCABN; ++v) {
            const int sel = sb[v] & 0xffff;
            const int bs = sb[v] >> 16;
            int p = wp[v] + mbcnt64(msk[v][0]) + mbcnt64(msk[v][1]) +
                    mbcnt64(msk[v][2]) + mbcnt64(msk[v][3]);
            #pragma unroll
            for (int i = 0; i < 4; ++i) {
                if (tok[i] == v) {
                    if (p < sel) out_topidx[(size_t)b * KSEL + bs + p] = (float)(t * 4 + i);
                    ++p;
                }
            }
        }
    }

    // --- wave 5 alone: app output + pooled + classifier (no barrier) ---
    if (w == 5) {
        const int4 sb03 = *(const int4*)&s_selbase[0];
        const int2 sb45 = *(const int2*)&s_selbase[4];
        const int sel6[VOCABN] = {sb03.x & 0xffff, sb03.y & 0xffff, sb03.z & 0xffff,
                                  sb03.w & 0xffff, sb45.x & 0xffff, sb45.y & 0xffff};
        const int j = lane & 31;
        const int half = lane >> 5;
        float part = 0.f;
        #pragma unroll
        for (int r = 0; r < 3; ++r) {
            const int v = 2 * r + half;
            float av = s_appb2[j];
            #pragma unroll
            for (int k = 0; k < DIM; ++k) av += s_ah[v * DIM + k] * s_appw2[k * DIM + j];
            part += (float)sel6[v] * av;
        }
        float pooled = (part + __shfl_xor(part, 32, 64)) * (1.f / (float)KSEL);
        float c = (lane < DIM / 2) ? s_clsb1[lane] : 0.f;
        #pragma unroll
        for (int d = 0; d < DIM; ++d) {
            const float pd = __shfl(pooled, d, 64);
            if (lane < DIM / 2) c += pd * s_clsw1[d * (DIM / 2) + lane];
        }
        float term = (lane < DIM / 2) ? fmaxf(c, 0.f) * s_clsw2[lane] : 0.f;
        term += __shfl_xor(term, 1, 64);
        term += __shfl_xor(term, 2, 64);
        term += __shfl_xor(term, 4, 64);
        term += __shfl_xor(term, 8, 64);
        if (lane == 0) out_pred[b] = 1.f / (1.f + expf(-(term + s_clsb2v)));
    }
}

extern "C" void kernel_launch(void* const* d_in, const int* in_sizes, int n_in,
                              void* d_out, int out_size, void* d_ws, size_t ws_size,
                              hipStream_t stream) {
    const int*   x      = (const int*)  d_in[0];
    const float* emb    = (const float*)d_in[1];
    const float* sel_w1 = (const float*)d_in[2];
    const float* sel_b1 = (const float*)d_in[3];
    const float* sel_w2 = (const float*)d_in[4];
    const float* sel_b2 = (const float*)d_in[5];
    const float* app_w1 = (const float*)d_in[6];
    const float* app_b1 = (const float*)d_in[7];
    const float* app_w2 = (const float*)d_in[8];
    const float* app_b2 = (const float*)d_in[9];
    const float* cls_w1 = (const float*)d_in[10];
    const float* cls_b1 = (const float*)d_in[11];
    const float* cls_w2 = (const float*)d_in[12];
    const float* cls_b2 = (const float*)d_in[13];

    float* out = (float*)d_out;
    float* out_pred   = out;                         // [256]
    float* out_topidx = out + BATCH;                 // [256*614] stored as float
    float* out_scores = out + BATCH + BATCH * KSEL;  // [256*4096]

    fused_row_kernel<<<BATCH, 1024, 0, stream>>>(
        x, emb, sel_w1, sel_b1, sel_w2, sel_b2,
        app_w1, app_b1, app_w2, app_b2,
        cls_w1, cls_b1, cls_w2, cls_b2,
        out_pred, out_topidx, out_scores);
}